// Round 2
// baseline (581.471 us; speedup 1.0000x reference)
//
#include <hip/hip_runtime.h>

// Problem constants
#define LQ  512     // rows per side (L1 == L2 == 512)
#define LKN 512
#define BB  32
#define DD  768
#define QT  16                // q rows per block
#define KT  32                // k rows per tile
#define NKT (LKN / KT)        // 16 k-tiles
#define DSL (DD / 4)          // 192: d-slice per wave

typedef float   f4    __attribute__((ext_vector_type(4)));
typedef _Float16 half8 __attribute__((ext_vector_type(8)));
typedef __fp16  fp16x2 __attribute__((ext_vector_type(2)));

union H8 { half8 h; unsigned int u[4]; };

__device__ __forceinline__ unsigned int pk2(float a, float b) {
    union { fp16x2 h; unsigned int u; } c;
    c.h = __builtin_amdgcn_cvt_pkrtz(a, b);
    return c.u;
}

__device__ __forceinline__ half8 cvt8(f4 a, f4 b) {
    H8 r;
    r.u[0] = pk2(a[0], a[1]); r.u[1] = pk2(a[2], a[3]);
    r.u[2] = pk2(b[0], b[1]); r.u[3] = pk2(b[2], b[3]);
    return r.h;
}

// One flash pass per (side, b, q-tile). 4 waves; wave w owns d-slice [192w,192w+192).
// S[16][32] computed as 4 partial d-slices, reduced via LDS; softmax wave-parallel;
// P stays in the PV A-fragment layout (lane: q=l&15, k=8*(l>>4)+j).
__global__ __launch_bounds__(256)
void coatt_flash(const float* __restrict__ x1, const float* __restrict__ m1,
                 const float* __restrict__ x2, const float* __restrict__ m2,
                 float* __restrict__ o1, float* __restrict__ o2)
{
    // XCD-aware decode: blocks of one (side,b) pair land on one XCD (K/V L2 reuse).
    const int i    = blockIdx.x;          // 0..2047
    const int xcd  = i & 7;
    const int j    = i >> 3;              // 0..255
    const int pair = xcd * 8 + (j >> 5);  // 0..63
    const int qt   = j & 31;
    const int side = pair >> 5;           // 0: Q=x1,K=x2 ; 1: Q=x2,K=x1
    const int b    = pair & 31;

    const float* __restrict__ Q   = side ? x2 : x1;
    const float* __restrict__ K   = side ? x1 : x2;
    const float* __restrict__ MK  = side ? m1 : m2;
    float* __restrict__       OUT = side ? o2 : o1;

    const int tid  = threadIdx.x;
    const int lane = tid & 63;
    const int w    = tid >> 6;    // wave 0..3
    const int lr   = lane & 15;
    const int lg   = lane >> 4;   // 0..3

    const int q0 = qt * QT;
    const int d0 = w * DSL;

    __shared__ float sred[4][QT][36];   // padded: write bank = (16lg+4r+lr)%32 -> 2-way (free)
    __shared__ float mask_s[LKN];

    for (int t = tid; t < LKN; t += 256) mask_s[t] = MK[t * BB + b];

    // --- Q fragments (A-operand, f16): lane holds Q[q0+lr][d0 + ks*32 + lg*8 + jj]
    half8 qf[6];
    {
        const float* qrow = Q + ((q0 + lr) * BB + b) * DD + d0 + lg * 8;
        #pragma unroll
        for (int ks = 0; ks < 6; ++ks) {
            f4 a = *(const f4*)(qrow + ks * 32);
            f4 c = *(const f4*)(qrow + ks * 32 + 4);
            qf[ks] = cvt8(a, c);
        }
    }

    f4 acc[12];                         // O[q=4lg+r][d0 + nt*16 + lr]
    #pragma unroll
    for (int t = 0; t < 12; ++t) acc[t] = f4{0.f, 0.f, 0.f, 0.f};
    float Mrun = -3.0e38f, Lrun = 0.f;  // running stats for q = q0 + lr (per lane)

    for (int kt = 0; kt < NKT; ++kt) {
        const int k0 = kt * KT;

        // --- S partial over this wave's d-slice: S[16 q][32 kr]
        f4 s0 = {0.f,0.f,0.f,0.f}, s1 = {0.f,0.f,0.f,0.f};
        {
            const float* kb0 = K + ((k0 + lr) * BB + b) * DD + d0 + lg * 8;        // kr = lr
            const float* kb1 = kb0 + 16 * BB * DD;                                  // kr = 16+lr
            #pragma unroll
            for (int ks = 0; ks < 6; ++ks) {
                f4 a0 = *(const f4*)(kb0 + ks * 32);
                f4 c0 = *(const f4*)(kb0 + ks * 32 + 4);
                s0 = __builtin_amdgcn_mfma_f32_16x16x32_f16(qf[ks], cvt8(a0, c0), s0, 0, 0, 0);
                f4 a1 = *(const f4*)(kb1 + ks * 32);
                f4 c1 = *(const f4*)(kb1 + ks * 32 + 4);
                s1 = __builtin_amdgcn_mfma_f32_16x16x32_f16(qf[ks], cvt8(a1, c1), s1, 0, 0, 0);
            }
        }

        // --- cross-wave reduce via LDS (C-layout: col=lane&15, row=4*(lane>>4)+r)
        __syncthreads();   // prior iteration's sred reads complete
        #pragma unroll
        for (int r = 0; r < 4; ++r) {
            sred[w][4 * lg + r][lr]      = s0[r];
            sred[w][4 * lg + r][16 + lr] = s1[r];
        }
        __syncthreads();

        // each wave reads full S at its PV-A-frag positions: q=lr, kr=lg*8+jj
        f4 sa = {0.f,0.f,0.f,0.f}, sb = {0.f,0.f,0.f,0.f};
        #pragma unroll
        for (int ww = 0; ww < 4; ++ww) {
            sa += *(const f4*)&sred[ww][lr][lg * 8];
            sb += *(const f4*)&sred[ww][lr][lg * 8 + 4];
        }

        // --- online softmax (max over UNMASKED scores, mask applied to weights)
        float tmax = fmaxf(fmaxf(fmaxf(sa[0], sa[1]), fmaxf(sa[2], sa[3])),
                           fmaxf(fmaxf(sb[0], sb[1]), fmaxf(sb[2], sb[3])));
        tmax = fmaxf(tmax, __shfl_xor(tmax, 16));
        tmax = fmaxf(tmax, __shfl_xor(tmax, 32));
        const float Mnew  = fmaxf(Mrun, tmax);
        const float scale = __expf(Mrun - Mnew);   // iter 0: exp(-huge)=0
        float p[8];
        float psum = 0.f;
        const float* mrow = &mask_s[k0 + lg * 8];
        #pragma unroll
        for (int t = 0; t < 4; ++t) { p[t]     = __expf(sa[t] - Mnew) * mrow[t];     psum += p[t]; }
        #pragma unroll
        for (int t = 0; t < 4; ++t) { p[4 + t] = __expf(sb[t] - Mnew) * mrow[4 + t]; psum += p[4 + t]; }
        psum += __shfl_xor(psum, 16);
        psum += __shfl_xor(psum, 32);
        Lrun = Lrun * scale + psum;
        Mrun = Mnew;

        H8 pf;
        pf.u[0] = pk2(p[0], p[1]); pf.u[1] = pk2(p[2], p[3]);
        pf.u[2] = pk2(p[4], p[5]); pf.u[3] = pk2(p[6], p[7]);

        // broadcast per-row rescale (stats live at q=lane&15; O rows are q=4lg+r)
        float sc[4];
        #pragma unroll
        for (int r = 0; r < 4; ++r) sc[r] = __shfl(scale, (lane & 48) + 4 * lg + r);
        #pragma unroll
        for (int t = 0; t < 12; ++t) {
            acc[t][0] *= sc[0]; acc[t][1] *= sc[1];
            acc[t][2] *= sc[2]; acc[t][3] *= sc[3];
        }

        // --- PV: O[q][d] += P[q][kr] * V[kr][d], V read direct from global (L2-hot)
        const float* vb = K + ((k0 + lg * 8) * BB + b) * DD + d0 + lr;   // row kr=lg*8, col d0+lr
        #pragma unroll
        for (int nt = 0; nt < 12; ++nt) {
            const float* vp = vb + nt * 16;
            float vv[8];
            #pragma unroll
            for (int t = 0; t < 8; ++t) vv[t] = vp[t * BB * DD];
            H8 vf;
            vf.u[0] = pk2(vv[0], vv[1]); vf.u[1] = pk2(vv[2], vv[3]);
            vf.u[2] = pk2(vv[4], vv[5]); vf.u[3] = pk2(vv[6], vv[7]);
            acc[nt] = __builtin_amdgcn_mfma_f32_16x16x32_f16(pf.h, vf.h, acc[nt], 0, 0, 0);
        }
    }

    // --- epilogue: normalize by (L + eps), broadcast per-row, store f32
    float il[4];
    {
        const float inv = 1.f / (Lrun + 1e-8f);
        #pragma unroll
        for (int r = 0; r < 4; ++r) il[r] = __shfl(inv, (lane & 48) + 4 * lg + r);
    }
    #pragma unroll
    for (int nt = 0; nt < 12; ++nt) {
        #pragma unroll
        for (int r = 0; r < 4; ++r) {
            OUT[((q0 + 4 * lg + r) * BB + b) * DD + d0 + nt * 16 + lr] = acc[nt][r] * il[r];
        }
    }
}

extern "C" void kernel_launch(void* const* d_in, const int* in_sizes, int n_in,
                              void* d_out, int out_size, void* d_ws, size_t ws_size,
                              hipStream_t stream) {
    (void)in_sizes; (void)n_in; (void)d_ws; (void)ws_size; (void)out_size;
    const float* x1 = (const float*)d_in[0];
    const float* m1 = (const float*)d_in[1];
    const float* x2 = (const float*)d_in[2];
    const float* m2 = (const float*)d_in[3];
    float* o1 = (float*)d_out;
    float* o2 = o1 + (size_t)LQ * BB * DD;
    // 2 sides x 32 batches x 32 q-tiles = 2048 blocks, XCD-swizzled in-kernel
    coatt_flash<<<2048, 256, 0, stream>>>(x1, m1, x2, m2, o1, o2);
}

// Round 3
// 408.927 us; speedup vs baseline: 1.4219x; 1.4219x over previous
//
#include <hip/hip_runtime.h>

// Problem constants
#define LQ  512
#define LKN 512
#define BB  32
#define DD  768
#define QT  16                // q rows per block
#define KT  32                // k rows per tile
#define NKT (LKN / KT)        // 16 k-tiles
#define DSL (DD / 4)          // 192: d-slice per wave

typedef float    f4     __attribute__((ext_vector_type(4)));
typedef _Float16 half8  __attribute__((ext_vector_type(8)));
typedef _Float16 half4  __attribute__((ext_vector_type(4)));
typedef __fp16   fp16x2 __attribute__((ext_vector_type(2)));

union H8 { half8 h; unsigned int u[4]; };

__device__ __forceinline__ unsigned int pk2(float a, float b) {
    union { fp16x2 h; unsigned int u; } c;
    c.h = __builtin_amdgcn_cvt_pkrtz(a, b);
    return c.u;
}

__device__ __forceinline__ half8 cvt8(f4 a, f4 b) {
    H8 r;
    r.u[0] = pk2(a[0], a[1]); r.u[1] = pk2(a[2], a[3]);
    r.u[2] = pk2(b[0], b[1]); r.u[3] = pk2(b[2], b[3]);
    return r.h;
}

// ---------------------------------------------------------------------------
// Prep: per 64x64 (l,d) tile of one (side,b): write f16 copy (same layout)
// and f16 transposed copy [B][D][L] via LDS tile.
// ---------------------------------------------------------------------------
__global__ __launch_bounds__(256)
void prep_cvt_t(const float* __restrict__ x1, const float* __restrict__ x2,
                _Float16* __restrict__ xh1, _Float16* __restrict__ xh2,
                _Float16* __restrict__ xt1, _Float16* __restrict__ xt2)
{
    const int bi   = blockIdx.x;            // 2*32*8*12 = 6144
    const int side = bi / 3072;
    const int rem  = bi % 3072;
    const int b    = rem / 96;
    const int rem2 = rem % 96;
    const int l0   = (rem2 / 12) * 64;
    const int d0   = (rem2 % 12) * 64;

    const float* __restrict__ X  = side ? x2  : x1;
    _Float16* __restrict__    XH = side ? xh2 : xh1;
    _Float16* __restrict__    XT = side ? xt2 : xt1;

    __shared__ _Float16 T[64][72];          // padded

    const int tid = threadIdx.x;
    {
        const int r  = tid >> 4;            // 0..15
        const int c4 = (tid & 15) * 4;      // 0..60
        for (int rr = r; rr < 64; rr += 16) {
            const size_t idx = ((size_t)(l0 + rr) * BB + b) * DD + d0 + c4;
            f4 v = *(const f4*)(X + idx);
            half4 h;
            h[0] = (_Float16)v[0]; h[1] = (_Float16)v[1];
            h[2] = (_Float16)v[2]; h[3] = (_Float16)v[3];
            *(half4*)(XH + idx) = h;
            *(half4*)&T[rr][c4] = h;
        }
    }
    __syncthreads();
    {
        const int d  = tid >> 2;            // 0..63
        const int lq = (tid & 3) * 16;      // 0,16,32,48
        half8 a, c;
        #pragma unroll
        for (int i = 0; i < 8; ++i) { a[i] = T[lq + i][d]; c[i] = T[lq + 8 + i][d]; }
        _Float16* p = XT + ((size_t)b * DD + d0 + d) * LKN + l0 + lq;
        *(half8*)p       = a;
        *(half8*)(p + 8) = c;
    }
}

// ---------------------------------------------------------------------------
// Fast flash pass on f16 inputs. Qh/Kh: [L][B][D] f16; VT: [B][D][L] f16.
// ---------------------------------------------------------------------------
__global__ __launch_bounds__(256)
void coatt_flash_f16(const _Float16* __restrict__ xh1, const _Float16* __restrict__ xh2,
                     const _Float16* __restrict__ xt1, const _Float16* __restrict__ xt2,
                     const float* __restrict__ m1, const float* __restrict__ m2,
                     float* __restrict__ o1, float* __restrict__ o2)
{
    const int i    = blockIdx.x;
    const int xcd  = i & 7;
    const int j    = i >> 3;
    const int pair = xcd * 8 + (j >> 5);
    const int qt   = j & 31;
    const int side = pair >> 5;
    const int b    = pair & 31;

    const _Float16* __restrict__ Qh = side ? xh2 : xh1;
    const _Float16* __restrict__ Kh = side ? xh1 : xh2;
    const _Float16* __restrict__ VT = side ? xt1 : xt2;   // transpose of K-side
    const float* __restrict__    MK = side ? m1  : m2;
    float* __restrict__         OUT = side ? o2  : o1;

    const int tid  = threadIdx.x;
    const int lane = tid & 63;
    const int w    = tid >> 6;
    const int lr   = lane & 15;
    const int lg   = lane >> 4;

    const int q0 = qt * QT;
    const int d0 = w * DSL;

    __shared__ float sred[4][QT][36];
    __shared__ float mask_s[LKN];

    for (int t = tid; t < LKN; t += 256) mask_s[t] = MK[t * BB + b];

    // Q fragments: lane holds Q[q0+lr][d0 + ks*32 + lg*8 + jj]
    half8 qf[6];
    {
        const _Float16* qrow = Qh + ((size_t)(q0 + lr) * BB + b) * DD + d0 + lg * 8;
        #pragma unroll
        for (int ks = 0; ks < 6; ++ks) qf[ks] = *(const half8*)(qrow + ks * 32);
    }

    f4 acc[12];
    #pragma unroll
    for (int t = 0; t < 12; ++t) acc[t] = f4{0.f, 0.f, 0.f, 0.f};
    float Mrun = -3.0e38f, Lrun = 0.f;

    for (int kt = 0; kt < NKT; ++kt) {
        const int k0 = kt * KT;

        // S partial over this wave's d-slice
        f4 s0 = {0.f,0.f,0.f,0.f}, s1 = {0.f,0.f,0.f,0.f};
        {
            const _Float16* kb0 = Kh + ((size_t)(k0 + lr) * BB + b) * DD + d0 + lg * 8;
            const _Float16* kb1 = kb0 + (size_t)16 * BB * DD;
            #pragma unroll
            for (int ks = 0; ks < 6; ++ks) {
                s0 = __builtin_amdgcn_mfma_f32_16x16x32_f16(qf[ks], *(const half8*)(kb0 + ks * 32), s0, 0, 0, 0);
                s1 = __builtin_amdgcn_mfma_f32_16x16x32_f16(qf[ks], *(const half8*)(kb1 + ks * 32), s1, 0, 0, 0);
            }
        }

        // cross-wave reduce via LDS
        __syncthreads();
        #pragma unroll
        for (int r = 0; r < 4; ++r) {
            sred[w][4 * lg + r][lr]      = s0[r];
            sred[w][4 * lg + r][16 + lr] = s1[r];
        }
        __syncthreads();

        f4 sa = {0.f,0.f,0.f,0.f}, sb = {0.f,0.f,0.f,0.f};
        #pragma unroll
        for (int ww = 0; ww < 4; ++ww) {
            sa += *(const f4*)&sred[ww][lr][lg * 8];
            sb += *(const f4*)&sred[ww][lr][lg * 8 + 4];
        }

        // online softmax
        float tmax = fmaxf(fmaxf(fmaxf(sa[0], sa[1]), fmaxf(sa[2], sa[3])),
                           fmaxf(fmaxf(sb[0], sb[1]), fmaxf(sb[2], sb[3])));
        tmax = fmaxf(tmax, __shfl_xor(tmax, 16));
        tmax = fmaxf(tmax, __shfl_xor(tmax, 32));
        const float Mnew  = fmaxf(Mrun, tmax);
        const float scale = __expf(Mrun - Mnew);
        float p[8];
        float psum = 0.f;
        const float* mrow = &mask_s[k0 + lg * 8];
        #pragma unroll
        for (int t = 0; t < 4; ++t) { p[t]     = __expf(sa[t] - Mnew) * mrow[t];     psum += p[t]; }
        #pragma unroll
        for (int t = 0; t < 4; ++t) { p[4 + t] = __expf(sb[t] - Mnew) * mrow[4 + t]; psum += p[4 + t]; }
        psum += __shfl_xor(psum, 16);
        psum += __shfl_xor(psum, 32);
        Lrun = Lrun * scale + psum;
        Mrun = Mnew;

        H8 pf;
        pf.u[0] = pk2(p[0], p[1]); pf.u[1] = pk2(p[2], p[3]);
        pf.u[2] = pk2(p[4], p[5]); pf.u[3] = pk2(p[6], p[7]);

        float sc[4];
        #pragma unroll
        for (int r = 0; r < 4; ++r) sc[r] = __shfl(scale, (lane & 48) + 4 * lg + r);
        #pragma unroll
        for (int t = 0; t < 12; ++t) {
            acc[t][0] *= sc[0]; acc[t][1] *= sc[1];
            acc[t][2] *= sc[2]; acc[t][3] *= sc[3];
        }

        // PV: B-frag = VT[b][d0+nt*16+lr][k0+lg*8 .. +7] — one dwordx4 per nt
        const _Float16* vb = VT + ((size_t)b * DD + d0 + lr) * LKN + k0 + lg * 8;
        #pragma unroll
        for (int nt = 0; nt < 12; ++nt) {
            half8 vf = *(const half8*)(vb + (size_t)nt * 16 * LKN);
            acc[nt] = __builtin_amdgcn_mfma_f32_16x16x32_f16(pf.h, vf, acc[nt], 0, 0, 0);
        }
    }

    float il[4];
    {
        const float inv = 1.f / (Lrun + 1e-8f);
        #pragma unroll
        for (int r = 0; r < 4; ++r) il[r] = __shfl(inv, (lane & 48) + 4 * lg + r);
    }
    #pragma unroll
    for (int nt = 0; nt < 12; ++nt) {
        #pragma unroll
        for (int r = 0; r < 4; ++r) {
            OUT[((size_t)(q0 + 4 * lg + r) * BB + b) * DD + d0 + nt * 16 + lr] = acc[nt][r] * il[r];
        }
    }
}

// ---------------------------------------------------------------------------
// Fallback (f32 direct) — the round-2 passing kernel, used if ws too small.
// ---------------------------------------------------------------------------
__global__ __launch_bounds__(256)
void coatt_flash_f32(const float* __restrict__ x1, const float* __restrict__ m1,
                     const float* __restrict__ x2, const float* __restrict__ m2,
                     float* __restrict__ o1, float* __restrict__ o2)
{
    const int i    = blockIdx.x;
    const int xcd  = i & 7;
    const int j    = i >> 3;
    const int pair = xcd * 8 + (j >> 5);
    const int qt   = j & 31;
    const int side = pair >> 5;
    const int b    = pair & 31;

    const float* __restrict__ Q   = side ? x2 : x1;
    const float* __restrict__ K   = side ? x1 : x2;
    const float* __restrict__ MK  = side ? m1 : m2;
    float* __restrict__       OUT = side ? o2 : o1;

    const int tid  = threadIdx.x;
    const int lane = tid & 63;
    const int w    = tid >> 6;
    const int lr   = lane & 15;
    const int lg   = lane >> 4;

    const int q0 = qt * QT;
    const int d0 = w * DSL;

    __shared__ float sred[4][QT][36];
    __shared__ float mask_s[LKN];

    for (int t = tid; t < LKN; t += 256) mask_s[t] = MK[t * BB + b];

    half8 qf[6];
    {
        const float* qrow = Q + ((q0 + lr) * BB + b) * DD + d0 + lg * 8;
        #pragma unroll
        for (int ks = 0; ks < 6; ++ks) {
            f4 a = *(const f4*)(qrow + ks * 32);
            f4 c = *(const f4*)(qrow + ks * 32 + 4);
            qf[ks] = cvt8(a, c);
        }
    }

    f4 acc[12];
    #pragma unroll
    for (int t = 0; t < 12; ++t) acc[t] = f4{0.f, 0.f, 0.f, 0.f};
    float Mrun = -3.0e38f, Lrun = 0.f;

    for (int kt = 0; kt < NKT; ++kt) {
        const int k0 = kt * KT;
        f4 s0 = {0.f,0.f,0.f,0.f}, s1 = {0.f,0.f,0.f,0.f};
        {
            const float* kb0 = K + ((k0 + lr) * BB + b) * DD + d0 + lg * 8;
            const float* kb1 = kb0 + 16 * BB * DD;
            #pragma unroll
            for (int ks = 0; ks < 6; ++ks) {
                f4 a0 = *(const f4*)(kb0 + ks * 32);
                f4 c0 = *(const f4*)(kb0 + ks * 32 + 4);
                s0 = __builtin_amdgcn_mfma_f32_16x16x32_f16(qf[ks], cvt8(a0, c0), s0, 0, 0, 0);
                f4 a1 = *(const f4*)(kb1 + ks * 32);
                f4 c1 = *(const f4*)(kb1 + ks * 32 + 4);
                s1 = __builtin_amdgcn_mfma_f32_16x16x32_f16(qf[ks], cvt8(a1, c1), s1, 0, 0, 0);
            }
        }
        __syncthreads();
        #pragma unroll
        for (int r = 0; r < 4; ++r) {
            sred[w][4 * lg + r][lr]      = s0[r];
            sred[w][4 * lg + r][16 + lr] = s1[r];
        }
        __syncthreads();
        f4 sa = {0.f,0.f,0.f,0.f}, sb = {0.f,0.f,0.f,0.f};
        #pragma unroll
        for (int ww = 0; ww < 4; ++ww) {
            sa += *(const f4*)&sred[ww][lr][lg * 8];
            sb += *(const f4*)&sred[ww][lr][lg * 8 + 4];
        }
        float tmax = fmaxf(fmaxf(fmaxf(sa[0], sa[1]), fmaxf(sa[2], sa[3])),
                           fmaxf(fmaxf(sb[0], sb[1]), fmaxf(sb[2], sb[3])));
        tmax = fmaxf(tmax, __shfl_xor(tmax, 16));
        tmax = fmaxf(tmax, __shfl_xor(tmax, 32));
        const float Mnew  = fmaxf(Mrun, tmax);
        const float scale = __expf(Mrun - Mnew);
        float p[8];
        float psum = 0.f;
        const float* mrow = &mask_s[k0 + lg * 8];
        #pragma unroll
        for (int t = 0; t < 4; ++t) { p[t]     = __expf(sa[t] - Mnew) * mrow[t];     psum += p[t]; }
        #pragma unroll
        for (int t = 0; t < 4; ++t) { p[4 + t] = __expf(sb[t] - Mnew) * mrow[4 + t]; psum += p[4 + t]; }
        psum += __shfl_xor(psum, 16);
        psum += __shfl_xor(psum, 32);
        Lrun = Lrun * scale + psum;
        Mrun = Mnew;

        H8 pf;
        pf.u[0] = pk2(p[0], p[1]); pf.u[1] = pk2(p[2], p[3]);
        pf.u[2] = pk2(p[4], p[5]); pf.u[3] = pk2(p[6], p[7]);

        float sc[4];
        #pragma unroll
        for (int r = 0; r < 4; ++r) sc[r] = __shfl(scale, (lane & 48) + 4 * lg + r);
        #pragma unroll
        for (int t = 0; t < 12; ++t) {
            acc[t][0] *= sc[0]; acc[t][1] *= sc[1];
            acc[t][2] *= sc[2]; acc[t][3] *= sc[3];
        }

        const float* vb = K + ((k0 + lg * 8) * BB + b) * DD + d0 + lr;
        #pragma unroll
        for (int nt = 0; nt < 12; ++nt) {
            const float* vp = vb + nt * 16;
            float vv[8];
            #pragma unroll
            for (int t = 0; t < 8; ++t) vv[t] = vp[t * BB * DD];
            H8 vf;
            vf.u[0] = pk2(vv[0], vv[1]); vf.u[1] = pk2(vv[2], vv[3]);
            vf.u[2] = pk2(vv[4], vv[5]); vf.u[3] = pk2(vv[6], vv[7]);
            acc[nt] = __builtin_amdgcn_mfma_f32_16x16x32_f16(pf.h, vf.h, acc[nt], 0, 0, 0);
        }
    }

    float il[4];
    {
        const float inv = 1.f / (Lrun + 1e-8f);
        #pragma unroll
        for (int r = 0; r < 4; ++r) il[r] = __shfl(inv, (lane & 48) + 4 * lg + r);
    }
    #pragma unroll
    for (int nt = 0; nt < 12; ++nt) {
        #pragma unroll
        for (int r = 0; r < 4; ++r) {
            OUT[((q0 + 4 * lg + r) * BB + b) * DD + d0 + nt * 16 + lr] = acc[nt][r] * il[r];
        }
    }
}

extern "C" void kernel_launch(void* const* d_in, const int* in_sizes, int n_in,
                              void* d_out, int out_size, void* d_ws, size_t ws_size,
                              hipStream_t stream) {
    (void)in_sizes; (void)n_in; (void)out_size;
    const float* x1 = (const float*)d_in[0];
    const float* m1 = (const float*)d_in[1];
    const float* x2 = (const float*)d_in[2];
    const float* m2 = (const float*)d_in[3];
    float* o1 = (float*)d_out;
    float* o2 = o1 + (size_t)LQ * BB * DD;

    const size_t ELEMS = (size_t)LQ * BB * DD;       // 12,582,912 per side
    const size_t NEED  = 4 * ELEMS * sizeof(_Float16); // xh1,xh2,xt1,xt2 = 96 MiB

    if (ws_size >= NEED) {
        _Float16* xh1 = (_Float16*)d_ws;
        _Float16* xh2 = xh1 + ELEMS;
        _Float16* xt1 = xh2 + ELEMS;
        _Float16* xt2 = xt1 + ELEMS;
        prep_cvt_t<<<6144, 256, 0, stream>>>(x1, x2, xh1, xh2, xt1, xt2);
        coatt_flash_f16<<<2048, 256, 0, stream>>>(xh1, xh2, xt1, xt2, m1, m2, o1, o2);
    } else {
        coatt_flash_f32<<<2048, 256, 0, stream>>>(x1, m1, x2, m2, o1, o2);
    }
}

// Round 4
// 278.239 us; speedup vs baseline: 2.0898x; 1.4697x over previous
//
#include <hip/hip_runtime.h>

// Problem constants
#define LQ  512
#define LKN 512
#define BB  32
#define DD  768
#define QT  16                // q rows per block
#define KT  32                // k rows per tile
#define NKT (LKN / KT)        // 16 k-tiles
#define DSL (DD / 4)          // 192: d-slice per wave
#define ROWB (DD * 2)         // 1536 bytes per K-tile row in LDS

typedef float    f4     __attribute__((ext_vector_type(4)));
typedef _Float16 half8  __attribute__((ext_vector_type(8)));
typedef _Float16 half4  __attribute__((ext_vector_type(4)));
typedef __fp16   fp16x2 __attribute__((ext_vector_type(2)));

union H8 { half8 h; unsigned int u[4]; };

__device__ __forceinline__ unsigned int pk2(float a, float b) {
    union { fp16x2 h; unsigned int u; } c;
    c.h = __builtin_amdgcn_cvt_pkrtz(a, b);
    return c.u;
}

__device__ __forceinline__ half8 cvt8(f4 a, f4 b) {
    H8 r;
    r.u[0] = pk2(a[0], a[1]); r.u[1] = pk2(a[2], a[3]);
    r.u[2] = pk2(b[0], b[1]); r.u[3] = pk2(b[2], b[3]);
    return r.h;
}

// ---------------------------------------------------------------------------
// Prep: per 64x64 (l,d) tile of one (side,b): f16 copy (same layout) and f16
// transposed copy [B][D][L] via LDS tile.
// ---------------------------------------------------------------------------
__global__ __launch_bounds__(256)
void prep_cvt_t(const float* __restrict__ x1, const float* __restrict__ x2,
                _Float16* __restrict__ xh1, _Float16* __restrict__ xh2,
                _Float16* __restrict__ xt1, _Float16* __restrict__ xt2)
{
    const int bi   = blockIdx.x;            // 2*32*8*12 = 6144
    const int side = bi / 3072;
    const int rem  = bi % 3072;
    const int b    = rem / 96;
    const int rem2 = rem % 96;
    const int l0   = (rem2 / 12) * 64;
    const int d0   = (rem2 % 12) * 64;

    const float* __restrict__ X  = side ? x2  : x1;
    _Float16* __restrict__    XH = side ? xh2 : xh1;
    _Float16* __restrict__    XT = side ? xt2 : xt1;

    __shared__ _Float16 T[64][72];          // padded

    const int tid = threadIdx.x;
    {
        const int r  = tid >> 4;            // 0..15
        const int c4 = (tid & 15) * 4;      // 0..60
        for (int rr = r; rr < 64; rr += 16) {
            const size_t idx = ((size_t)(l0 + rr) * BB + b) * DD + d0 + c4;
            f4 v = *(const f4*)(X + idx);
            half4 h;
            h[0] = (_Float16)v[0]; h[1] = (_Float16)v[1];
            h[2] = (_Float16)v[2]; h[3] = (_Float16)v[3];
            *(half4*)(XH + idx) = h;
            *(half4*)&T[rr][c4] = h;
        }
    }
    __syncthreads();
    {
        const int d  = tid >> 2;            // 0..63
        const int lq = (tid & 3) * 16;      // 0,16,32,48
        half8 a, c;
        #pragma unroll
        for (int i = 0; i < 8; ++i) { a[i] = T[lq + i][d]; c[i] = T[lq + 8 + i][d]; }
        _Float16* p = XT + ((size_t)b * DD + d0 + d) * LKN + l0 + lq;
        *(half8*)p       = a;
        *(half8*)(p + 8) = c;
    }
}

// ---------------------------------------------------------------------------
// Flash pass, K-tile staged in LDS (XOR-swizzled), V from VT [B][D][L].
// ---------------------------------------------------------------------------
__global__ __launch_bounds__(256, 2)
void coatt_flash_f16(const _Float16* __restrict__ xh1, const _Float16* __restrict__ xh2,
                     const _Float16* __restrict__ xt1, const _Float16* __restrict__ xt2,
                     const float* __restrict__ m1, const float* __restrict__ m2,
                     float* __restrict__ o1, float* __restrict__ o2)
{
    const int i    = blockIdx.x;
    const int xcd  = i & 7;
    const int j    = i >> 3;
    const int pair = xcd * 8 + (j >> 5);
    const int qt   = j & 31;
    const int side = pair >> 5;
    const int b    = pair & 31;

    const _Float16* __restrict__ Qh = side ? xh2 : xh1;
    const _Float16* __restrict__ Kh = side ? xh1 : xh2;
    const _Float16* __restrict__ VT = side ? xt1 : xt2;
    const float* __restrict__    MK = side ? m1  : m2;
    float* __restrict__         OUT = side ? o2  : o1;

    const int tid  = threadIdx.x;
    const int lane = tid & 63;
    const int w    = tid >> 6;
    const int lr   = lane & 15;
    const int lg   = lane >> 4;

    const int q0 = qt * QT;
    const int d0 = w * DSL;

    __shared__ _Float16 ktile[KT * DD];     // 48 KB, swizzled: byte = k*1536 + ((d*2)^((k&7)<<4))
    __shared__ float sred[4][QT][36];
    __shared__ float mask_s[LKN];
    char* const klds = (char*)ktile;

    for (int t = tid; t < LKN; t += 256) mask_s[t] = MK[t * BB + b];

    // Per-wave staging map: wave w owns k-tile rows 8w..8w+7 (12 KB = 12 chunks).
    int dstoff[12], srcoff[12];
    #pragma unroll
    for (int c = 0; c < 12; ++c) {
        const int e   = c * 512 + lane * 8;       // f16 elem within wave region
        const int kl  = e / 768;
        const int d0e = e - kl * 768;
        const int kk  = w * 8 + kl;               // local k row (kk&7 == kl&7... == (w*8+kl)&7 = kl&7? no: (8w+kl)&7 = kl&7 since 8w≡0) 
        dstoff[c] = kk * ROWB + ((d0e * 2) ^ ((kk & 7) << 4));
        srcoff[c] = kk * (BB * DD) + d0e;         // elems; add base (b*DD + kt*32*BB*DD)
    }

    // Q fragments: lane holds Q[q0+lr][d0 + ks*32 + lg*8 + jj]
    half8 qf[6];
    {
        const _Float16* qrow = Qh + ((size_t)(q0 + lr) * BB + b) * DD + d0 + lg * 8;
        #pragma unroll
        for (int ks = 0; ks < 6; ++ks) qf[ks] = *(const half8*)(qrow + ks * 32);
    }

    // Stage tile 0
    half8 st[12];
    {
        const _Float16* ksrc = Kh + (size_t)b * DD;
        #pragma unroll
        for (int c = 0; c < 12; ++c) st[c] = *(const half8*)(ksrc + srcoff[c]);
        #pragma unroll
        for (int c = 0; c < 12; ++c) *(half8*)(klds + dstoff[c]) = st[c];
    }

    f4 acc[12];
    #pragma unroll
    for (int t = 0; t < 12; ++t) acc[t] = f4{0.f, 0.f, 0.f, 0.f};
    float Mrun = -3.0e38f, Lrun = 0.f;

    __syncthreads();

    for (int kt = 0; kt < NKT; ++kt) {
        // 1. prefetch next K-tile into regs (latency hides under this whole iter)
        if (kt < NKT - 1) {
            const _Float16* nsrc = Kh + (size_t)b * DD + (size_t)(kt + 1) * KT * BB * DD;
            #pragma unroll
            for (int c = 0; c < 12; ++c) st[c] = *(const half8*)(nsrc + srcoff[c]);
        }

        // 2. S partial over this wave's d-slice, K-frags from swizzled LDS
        f4 s0 = {0.f,0.f,0.f,0.f}, s1 = {0.f,0.f,0.f,0.f};
        #pragma unroll
        for (int ks = 0; ks < 6; ++ks) {
            const int dby = (d0 + ks * 32 + lg * 8) * 2;
            const int sw  = (lr & 7) << 4;
            const half8 k0f = *(const half8*)(klds + lr * ROWB        + (dby ^ sw));
            const half8 k1f = *(const half8*)(klds + (16 + lr) * ROWB + (dby ^ sw));
            s0 = __builtin_amdgcn_mfma_f32_16x16x32_f16(qf[ks], k0f, s0, 0, 0, 0);
            s1 = __builtin_amdgcn_mfma_f32_16x16x32_f16(qf[ks], k1f, s1, 0, 0, 0);
        }

        // 3. cross-wave reduce staging (also proves this wave is done reading ktile)
        #pragma unroll
        for (int r = 0; r < 4; ++r) {
            sred[w][4 * lg + r][lr]      = s0[r];
            sred[w][4 * lg + r][16 + lr] = s1[r];
        }
        __syncthreads();   // [A] sred visible; all waves done reading ktile

        // 5a. prefetch V fragments (independent of softmax)
        half8 vf[12];
        {
            const _Float16* vb = VT + ((size_t)b * DD + d0 + lr) * LKN + kt * KT + lg * 8;
            #pragma unroll
            for (int nt = 0; nt < 12; ++nt) vf[nt] = *(const half8*)(vb + (size_t)nt * 16 * LKN);
        }

        // 5b. sred read + online softmax
        f4 sa = {0.f,0.f,0.f,0.f}, sb = {0.f,0.f,0.f,0.f};
        #pragma unroll
        for (int ww = 0; ww < 4; ++ww) {
            sa += *(const f4*)&sred[ww][lr][lg * 8];
            sb += *(const f4*)&sred[ww][lr][lg * 8 + 4];
        }
        float tmax = fmaxf(fmaxf(fmaxf(sa[0], sa[1]), fmaxf(sa[2], sa[3])),
                           fmaxf(fmaxf(sb[0], sb[1]), fmaxf(sb[2], sb[3])));
        tmax = fmaxf(tmax, __shfl_xor(tmax, 16));
        tmax = fmaxf(tmax, __shfl_xor(tmax, 32));
        const float Mnew  = fmaxf(Mrun, tmax);
        const float scale = __expf(Mrun - Mnew);
        float p[8];
        float psum = 0.f;
        const float* mrow = &mask_s[kt * KT + lg * 8];
        #pragma unroll
        for (int t = 0; t < 4; ++t) { p[t]     = __expf(sa[t] - Mnew) * mrow[t];     psum += p[t]; }
        #pragma unroll
        for (int t = 0; t < 4; ++t) { p[4 + t] = __expf(sb[t] - Mnew) * mrow[4 + t]; psum += p[4 + t]; }
        psum += __shfl_xor(psum, 16);
        psum += __shfl_xor(psum, 32);
        Lrun = Lrun * scale + psum;
        Mrun = Mnew;

        H8 pf;
        pf.u[0] = pk2(p[0], p[1]); pf.u[1] = pk2(p[2], p[3]);
        pf.u[2] = pk2(p[4], p[5]); pf.u[3] = pk2(p[6], p[7]);

        float sc[4];
        #pragma unroll
        for (int r = 0; r < 4; ++r) sc[r] = __shfl(scale, (lane & 48) + 4 * lg + r);
        #pragma unroll
        for (int t = 0; t < 12; ++t) {
            acc[t][0] *= sc[0]; acc[t][1] *= sc[1];
            acc[t][2] *= sc[2]; acc[t][3] *= sc[3];
        }

        // 6. PV
        #pragma unroll
        for (int nt = 0; nt < 12; ++nt)
            acc[nt] = __builtin_amdgcn_mfma_f32_16x16x32_f16(pf.h, vf[nt], acc[nt], 0, 0, 0);

        // 7. write next tile to LDS (safe: barrier [A] proved all reads done)
        if (kt < NKT - 1) {
            #pragma unroll
            for (int c = 0; c < 12; ++c) *(half8*)(klds + dstoff[c]) = st[c];
        }
        __syncthreads();   // [B] next tile + sred buffer ready
    }

    float il[4];
    {
        const float inv = 1.f / (Lrun + 1e-8f);
        #pragma unroll
        for (int r = 0; r < 4; ++r) il[r] = __shfl(inv, (lane & 48) + 4 * lg + r);
    }
    #pragma unroll
    for (int nt = 0; nt < 12; ++nt) {
        #pragma unroll
        for (int r = 0; r < 4; ++r) {
            OUT[((size_t)(q0 + 4 * lg + r) * BB + b) * DD + d0 + nt * 16 + lr] = acc[nt][r] * il[r];
        }
    }
}

// ---------------------------------------------------------------------------
// Fallback (f32 direct) — round-2 passing kernel, used if ws too small.
// ---------------------------------------------------------------------------
__global__ __launch_bounds__(256)
void coatt_flash_f32(const float* __restrict__ x1, const float* __restrict__ m1,
                     const float* __restrict__ x2, const float* __restrict__ m2,
                     float* __restrict__ o1, float* __restrict__ o2)
{
    const int i    = blockIdx.x;
    const int xcd  = i & 7;
    const int j    = i >> 3;
    const int pair = xcd * 8 + (j >> 5);
    const int qt   = j & 31;
    const int side = pair >> 5;
    const int b    = pair & 31;

    const float* __restrict__ Q   = side ? x2 : x1;
    const float* __restrict__ K   = side ? x1 : x2;
    const float* __restrict__ MK  = side ? m1 : m2;
    float* __restrict__       OUT = side ? o2 : o1;

    const int tid  = threadIdx.x;
    const int lane = tid & 63;
    const int w    = tid >> 6;
    const int lr   = lane & 15;
    const int lg   = lane >> 4;

    const int q0 = qt * QT;
    const int d0 = w * DSL;

    __shared__ float sred[4][QT][36];
    __shared__ float mask_s[LKN];

    for (int t = tid; t < LKN; t += 256) mask_s[t] = MK[t * BB + b];

    half8 qf[6];
    {
        const float* qrow = Q + ((q0 + lr) * BB + b) * DD + d0 + lg * 8;
        #pragma unroll
        for (int ks = 0; ks < 6; ++ks) {
            f4 a = *(const f4*)(qrow + ks * 32);
            f4 c = *(const f4*)(qrow + ks * 32 + 4);
            qf[ks] = cvt8(a, c);
        }
    }

    f4 acc[12];
    #pragma unroll
    for (int t = 0; t < 12; ++t) acc[t] = f4{0.f, 0.f, 0.f, 0.f};
    float Mrun = -3.0e38f, Lrun = 0.f;

    for (int kt = 0; kt < NKT; ++kt) {
        const int k0 = kt * KT;
        f4 s0 = {0.f,0.f,0.f,0.f}, s1 = {0.f,0.f,0.f,0.f};
        {
            const float* kb0 = K + ((k0 + lr) * BB + b) * DD + d0 + lg * 8;
            const float* kb1 = kb0 + 16 * BB * DD;
            #pragma unroll
            for (int ks = 0; ks < 6; ++ks) {
                f4 a0 = *(const f4*)(kb0 + ks * 32);
                f4 c0 = *(const f4*)(kb0 + ks * 32 + 4);
                s0 = __builtin_amdgcn_mfma_f32_16x16x32_f16(qf[ks], cvt8(a0, c0), s0, 0, 0, 0);
                f4 a1 = *(const f4*)(kb1 + ks * 32);
                f4 c1 = *(const f4*)(kb1 + ks * 32 + 4);
                s1 = __builtin_amdgcn_mfma_f32_16x16x32_f16(qf[ks], cvt8(a1, c1), s1, 0, 0, 0);
            }
        }
        __syncthreads();
        #pragma unroll
        for (int r = 0; r < 4; ++r) {
            sred[w][4 * lg + r][lr]      = s0[r];
            sred[w][4 * lg + r][16 + lr] = s1[r];
        }
        __syncthreads();
        f4 sa = {0.f,0.f,0.f,0.f}, sb = {0.f,0.f,0.f,0.f};
        #pragma unroll
        for (int ww = 0; ww < 4; ++ww) {
            sa += *(const f4*)&sred[ww][lr][lg * 8];
            sb += *(const f4*)&sred[ww][lr][lg * 8 + 4];
        }
        float tmax = fmaxf(fmaxf(fmaxf(sa[0], sa[1]), fmaxf(sa[2], sa[3])),
                           fmaxf(fmaxf(sb[0], sb[1]), fmaxf(sb[2], sb[3])));
        tmax = fmaxf(tmax, __shfl_xor(tmax, 16));
        tmax = fmaxf(tmax, __shfl_xor(tmax, 32));
        const float Mnew  = fmaxf(Mrun, tmax);
        const float scale = __expf(Mrun - Mnew);
        float p[8];
        float psum = 0.f;
        const float* mrow = &mask_s[k0 + lg * 8];
        #pragma unroll
        for (int t = 0; t < 4; ++t) { p[t]     = __expf(sa[t] - Mnew) * mrow[t];     psum += p[t]; }
        #pragma unroll
        for (int t = 0; t < 4; ++t) { p[4 + t] = __expf(sb[t] - Mnew) * mrow[4 + t]; psum += p[4 + t]; }
        psum += __shfl_xor(psum, 16);
        psum += __shfl_xor(psum, 32);
        Lrun = Lrun * scale + psum;
        Mrun = Mnew;

        H8 pf;
        pf.u[0] = pk2(p[0], p[1]); pf.u[1] = pk2(p[2], p[3]);
        pf.u[2] = pk2(p[4], p[5]); pf.u[3] = pk2(p[6], p[7]);

        float sc[4];
        #pragma unroll
        for (int r = 0; r < 4; ++r) sc[r] = __shfl(scale, (lane & 48) + 4 * lg + r);
        #pragma unroll
        for (int t = 0; t < 12; ++t) {
            acc[t][0] *= sc[0]; acc[t][1] *= sc[1];
            acc[t][2] *= sc[2]; acc[t][3] *= sc[3];
        }

        const float* vb = K + ((k0 + lg * 8) * BB + b) * DD + d0 + lr;
        #pragma unroll
        for (int nt = 0; nt < 12; ++nt) {
            const float* vp = vb + nt * 16;
            float vv[8];
            #pragma unroll
            for (int t = 0; t < 8; ++t) vv[t] = vp[t * BB * DD];
            H8 vf;
            vf.u[0] = pk2(vv[0], vv[1]); vf.u[1] = pk2(vv[2], vv[3]);
            vf.u[2] = pk2(vv[4], vv[5]); vf.u[3] = pk2(vv[6], vv[7]);
            acc[nt] = __builtin_amdgcn_mfma_f32_16x16x32_f16(pf.h, vf.h, acc[nt], 0, 0, 0);
        }
    }

    float il[4];
    {
        const float inv = 1.f / (Lrun + 1e-8f);
        #pragma unroll
        for (int r = 0; r < 4; ++r) il[r] = __shfl(inv, (lane & 48) + 4 * lg + r);
    }
    #pragma unroll
    for (int nt = 0; nt < 12; ++nt) {
        #pragma unroll
        for (int r = 0; r < 4; ++r) {
            OUT[((q0 + 4 * lg + r) * BB + b) * DD + d0 + nt * 16 + lr] = acc[nt][r] * il[r];
        }
    }
}

extern "C" void kernel_launch(void* const* d_in, const int* in_sizes, int n_in,
                              void* d_out, int out_size, void* d_ws, size_t ws_size,
                              hipStream_t stream) {
    (void)in_sizes; (void)n_in; (void)out_size;
    const float* x1 = (const float*)d_in[0];
    const float* m1 = (const float*)d_in[1];
    const float* x2 = (const float*)d_in[2];
    const float* m2 = (const float*)d_in[3];
    float* o1 = (float*)d_out;
    float* o2 = o1 + (size_t)LQ * BB * DD;

    const size_t ELEMS = (size_t)LQ * BB * DD;
    const size_t NEED  = 4 * ELEMS * sizeof(_Float16);

    if (ws_size >= NEED) {
        _Float16* xh1 = (_Float16*)d_ws;
        _Float16* xh2 = xh1 + ELEMS;
        _Float16* xt1 = xh2 + ELEMS;
        _Float16* xt2 = xt1 + ELEMS;
        prep_cvt_t<<<6144, 256, 0, stream>>>(x1, x2, xh1, xh2, xt1, xt2);
        coatt_flash_f16<<<2048, 256, 0, stream>>>(xh1, xh2, xt1, xt2, m1, m2, o1, o2);
    } else {
        coatt_flash_f32<<<2048, 256, 0, stream>>>(x1, m1, x2, m2, o1, o2);
    }
}